// Round 3
// baseline (1204.947 us; speedup 1.0000x reference)
//
#include <hip/hip_runtime.h>
#include <math.h>

#define SEQ 2048
#define DM 256
#define NH 8
#define HD 32
#define DFF 512
#define BATCH 4
#define NTOK 8192            // BATCH*SEQ
#define EPS 1e-5f
#define QR 32                // q-rows per fused softmax+PV block
#define KT 256               // k-tile for fused softmax+PV

// ---------------------------------------------------------------- reductions
__device__ __forceinline__ float blockReduceSum256(float v, float* sm) {
    #pragma unroll
    for (int o = 32; o > 0; o >>= 1) v += __shfl_xor(v, o);
    int w = threadIdx.x >> 6;
    if ((threadIdx.x & 63) == 0) sm[w] = v;
    __syncthreads();
    float r = sm[0] + sm[1] + sm[2] + sm[3];
    __syncthreads();
    return r;
}

// ---------------------------------------------------------------- generic GEMM
// C[M,N] = act(A[M,K] @ W[K,N] + bias[N]); 64x64 tile, BK=16, 256 thr, 4x4/thr
template<bool RELU>
__global__ __launch_bounds__(256) void gemm_kernel(
    const float* __restrict__ A, const float* __restrict__ W,
    const float* __restrict__ bias, float* __restrict__ C,
    int M, int K, int N)
{
    __shared__ float As[64][17];
    __shared__ float Bs[16][64];
    const int row0 = blockIdx.y * 64, col0 = blockIdx.x * 64;
    const int tid = threadIdx.x;
    const int ty = tid >> 4, tx = tid & 15;
    float acc[4][4] = {};
    for (int kt = 0; kt < K; kt += 16) {
        {   // A tile 64x16 -> 256 float4, 1/thread
            int r = tid >> 2, c4 = (tid & 3) << 2;
            float4 v = *reinterpret_cast<const float4*>(&A[(size_t)(row0 + r) * K + kt + c4]);
            As[r][c4 + 0] = v.x; As[r][c4 + 1] = v.y; As[r][c4 + 2] = v.z; As[r][c4 + 3] = v.w;
        }
        {   // B tile 16x64 -> 256 float4, 1/thread
            int r = tid >> 4, c4 = (tid & 15) << 2;
            float4 v = *reinterpret_cast<const float4*>(&W[(size_t)(kt + r) * N + col0 + c4]);
            *reinterpret_cast<float4*>(&Bs[r][c4]) = v;
        }
        __syncthreads();
        #pragma unroll
        for (int k = 0; k < 16; k++) {
            float a[4], b[4];
            #pragma unroll
            for (int i = 0; i < 4; i++) a[i] = As[ty * 4 + i][k];
            #pragma unroll
            for (int j = 0; j < 4; j++) b[j] = Bs[k][tx * 4 + j];
            #pragma unroll
            for (int i = 0; i < 4; i++)
                #pragma unroll
                for (int j = 0; j < 4; j++)
                    acc[i][j] = fmaf(a[i], b[j], acc[i][j]);
        }
        __syncthreads();
    }
    #pragma unroll
    for (int i = 0; i < 4; i++) {
        float4 o;
        float* op = &o.x;
        #pragma unroll
        for (int j = 0; j < 4; j++) {
            float v = acc[i][j] + bias[col0 + tx * 4 + j];
            if (RELU) v = fmaxf(v, 0.f);
            op[j] = v;
        }
        *reinterpret_cast<float4*>(&C[(size_t)(row0 + ty * 4 + i) * N + col0 + tx * 4]) = o;
    }
}

// ---------------------------------------------------------------- energy: E = Q K^T / sqrt(hd)
// grid (S/64, S/64, B*H); Q,K in [B,S,DM] token layout (head h = cols h*32..)
__global__ __launch_bounds__(256) void energy_kernel(
    const float* __restrict__ Q, const float* __restrict__ Km,
    float* __restrict__ E)
{
    __shared__ float Qs[64][33];
    __shared__ float Ks[64][33];
    const int bh = blockIdx.z;
    const int b = bh >> 3, h = bh & 7;
    const int q0 = blockIdx.y * 64, k0 = blockIdx.x * 64;
    const int tid = threadIdx.x;
    const float* Qbase = Q + (size_t)b * SEQ * DM + h * HD;
    const float* Kbase = Km + (size_t)b * SEQ * DM + h * HD;
    #pragma unroll
    for (int i = 0; i < 2; i++) {   // 512 float4 across 256 threads
        int f4 = tid + i * 256;
        int r = f4 >> 3, c4 = (f4 & 7) << 2;
        float4 v = *reinterpret_cast<const float4*>(&Qbase[(size_t)(q0 + r) * DM + c4]);
        Qs[r][c4 + 0] = v.x; Qs[r][c4 + 1] = v.y; Qs[r][c4 + 2] = v.z; Qs[r][c4 + 3] = v.w;
        float4 w = *reinterpret_cast<const float4*>(&Kbase[(size_t)(k0 + r) * DM + c4]);
        Ks[r][c4 + 0] = w.x; Ks[r][c4 + 1] = w.y; Ks[r][c4 + 2] = w.z; Ks[r][c4 + 3] = w.w;
    }
    __syncthreads();
    const int ty = tid >> 4, tx = tid & 15;
    float acc[4][4] = {};
    #pragma unroll
    for (int d = 0; d < HD; d++) {
        float a[4], bv[4];
        #pragma unroll
        for (int i = 0; i < 4; i++) a[i] = Qs[ty * 4 + i][d];
        #pragma unroll
        for (int j = 0; j < 4; j++) bv[j] = Ks[tx * 4 + j][d];
        #pragma unroll
        for (int i = 0; i < 4; i++)
            #pragma unroll
            for (int j = 0; j < 4; j++)
                acc[i][j] = fmaf(a[i], bv[j], acc[i][j]);
    }
    const float rs = 0.17677669529663687f;   // 1/sqrt(32)
    float* Ebase = E + ((size_t)bh * SEQ + q0) * SEQ + k0;
    #pragma unroll
    for (int i = 0; i < 4; i++) {
        float4 o;
        o.x = acc[i][0] * rs; o.y = acc[i][1] * rs; o.z = acc[i][2] * rs; o.w = acc[i][3] * rs;
        *reinterpret_cast<float4*>(&Ebase[(size_t)(ty * 4 + i) * SEQ + tx * 4]) = o;
    }
}

// ---------------------------------------------------------------- fused softmax + PV
// Block: 32 q-rows of one (b,h). Phase 1: online (m,l) over the E rows.
// Phase 2: per 256-k tile: P = exp(E-m)/l -> write attn + LDS; ctx += P @ V.
// Thread map: r = tid>>3 (row), j = tid&7 (k-segment / 4-col group).
__global__ __launch_bounds__(256) void smpv_kernel(
    float* __restrict__ attn,        // in: E, out: softmax(E)
    const float* __restrict__ V,     // [B,S,DM] token layout
    float* __restrict__ ctx)         // [B,S,DM] token layout
{
    __shared__ float Ps[QR][260];    // pad 260: GEMM p-reads spread banks
    __shared__ float Vs[KT][36];     // pad 36: keeps float4 alignment + banks
    const int bh = blockIdx.y;
    const int b = bh >> 3, h = bh & 7;
    const int q0 = blockIdx.x * QR;
    const int tid = threadIdx.x;
    const int r = tid >> 3;
    const int j = tid & 7;

    float* Erow = attn + ((size_t)bh * SEQ + q0 + r) * SEQ;

    // ---- phase 1: online max/sum over this row (8 threads per row)
    float m = -1e30f, l = 0.f;
    for (int t = 0; t < 64; t++) {
        int k = (t * 8 + j) * 4;
        float4 a = *reinterpret_cast<const float4*>(&Erow[k]);
        float g = fmaxf(fmaxf(a.x, a.y), fmaxf(a.z, a.w));
        if (g > m) { l *= __expf(m - g); m = g; }
        l += __expf(a.x - m) + __expf(a.y - m) + __expf(a.z - m) + __expf(a.w - m);
    }
    #pragma unroll
    for (int o = 1; o < 8; o <<= 1) {   // merge across the row's 8 lanes
        float m2 = __shfl_xor(m, o);
        float l2 = __shfl_xor(l, o);
        float M = fmaxf(m, m2);
        l = l * __expf(m - M) + l2 * __expf(m2 - M);
        m = M;
    }
    const float invl = 1.f / l;

    // ---- phase 2: normalize + write attn + ctx accumulate
    const int c4 = j * 4;
    float acc[4] = {0.f, 0.f, 0.f, 0.f};
    const float* Vbase = V + (size_t)b * SEQ * DM + h * HD;

    for (int kt = 0; kt < SEQ; kt += KT) {
        #pragma unroll
        for (int t = 0; t < 8; t++) {        // E tile: 32 floats/thread
            int kk = (t * 8 + j) * 4;
            float4 a = *reinterpret_cast<const float4*>(&Erow[kt + kk]);
            float4 p;
            p.x = __expf(a.x - m) * invl;
            p.y = __expf(a.y - m) * invl;
            p.z = __expf(a.z - m) * invl;
            p.w = __expf(a.w - m) * invl;
            *reinterpret_cast<float4*>(&Erow[kt + kk]) = p;   // attn out
            *reinterpret_cast<float4*>(&Ps[r][kk]) = p;
        }
        #pragma unroll
        for (int t = 0; t < 8; t++) {        // V tile 256x32: 32 floats/thread
            int f = tid + t * 256;
            int kv = f >> 3, c = (f & 7) << 2;
            *reinterpret_cast<float4*>(&Vs[kv][c]) =
                *reinterpret_cast<const float4*>(&Vbase[(size_t)(kt + kv) * DM + c]);
        }
        __syncthreads();
        for (int k = 0; k < KT; k += 4) {
            float4 p4 = *reinterpret_cast<const float4*>(&Ps[r][k]);
            const float* pp = &p4.x;
            #pragma unroll
            for (int k2 = 0; k2 < 4; k2++) {
                float4 vv = *reinterpret_cast<const float4*>(&Vs[k + k2][c4]);
                float pv = pp[k2];
                acc[0] = fmaf(pv, vv.x, acc[0]);
                acc[1] = fmaf(pv, vv.y, acc[1]);
                acc[2] = fmaf(pv, vv.z, acc[2]);
                acc[3] = fmaf(pv, vv.w, acc[3]);
            }
        }
        __syncthreads();
    }
    float4 o;
    o.x = acc[0]; o.y = acc[1]; o.z = acc[2]; o.w = acc[3];
    *reinterpret_cast<float4*>(
        &ctx[(size_t)(b * SEQ + q0 + r) * DM + h * HD + c4]) = o;
}

// ---------------------------------------------------------------- residual + LayerNorm
__global__ __launch_bounds__(256) void ln_kernel(
    const float* __restrict__ A, const float* __restrict__ R,
    const float* __restrict__ g, const float* __restrict__ bb,
    float* __restrict__ O)
{
    __shared__ float sm[4];
    const size_t row = blockIdx.x;
    const int tid = threadIdx.x;
    float v = A[row * DM + tid] + R[row * DM + tid];
    float s = blockReduceSum256(v, sm);
    float mu = s * (1.f / DM);
    float d = v - mu;
    float s2 = blockReduceSum256(d * d, sm);
    float rstd = rsqrtf(s2 * (1.f / DM) + EPS);
    O[row * DM + tid] = d * rstd * g[tid] + bb[tid];
}

// ---------------------------------------------------------------- launch
extern "C" void kernel_launch(void* const* d_in, const int* in_sizes, int n_in,
                              void* d_out, int out_size, void* d_ws, size_t ws_size,
                              hipStream_t stream)
{
    const float* src = (const float*)d_in[0];
    const float* We  = (const float*)d_in[1];
    const float* be  = (const float*)d_in[2];
    const float* Wq  = (const float*)d_in[3];
    const float* bq  = (const float*)d_in[4];
    const float* Wk  = (const float*)d_in[5];
    const float* bk  = (const float*)d_in[6];
    const float* Wv  = (const float*)d_in[7];
    const float* bv  = (const float*)d_in[8];
    const float* Wo  = (const float*)d_in[9];
    const float* bo  = (const float*)d_in[10];
    const float* g1  = (const float*)d_in[11];
    const float* b1  = (const float*)d_in[12];
    const float* g2  = (const float*)d_in[13];
    const float* b2  = (const float*)d_in[14];
    const float* W1  = (const float*)d_in[15];
    const float* c1  = (const float*)d_in[16];
    const float* W2  = (const float*)d_in[17];
    const float* c2  = (const float*)d_in[18];

    float* out  = (float*)d_out;                    // [8192,256]
    float* attn = out + (size_t)NTOK * DM;          // [32,2048,2048]
    float* ws   = (float*)d_ws;

    const size_t M1 = 1024 * 1024;
    float* emb = ws;                 // 2M floats, live until LN1
    float* Qb  = ws + 2 * M1;        // 2M
    float* Kb  = ws + 4 * M1;        // 2M
    float* Vb  = ws + 6 * M1;        // 2M
    float* ctx = Qb;                 // reuse: Q dead after energy
    float* ao  = Vb;                 // attn_out; V dead after smpv
    float* x   = Kb;                 // K dead after energy
    float* hb  = ws;                 // 4M floats: emb+Q regions (both dead by FF1)
    float* ff  = Vb;                 // attn_out dead after LN1

    dim3 blk(256);
    // 1. emb = src@We + be           [8192,16]x[16,256]
    gemm_kernel<false><<<dim3(4, 128), blk, 0, stream>>>(src, We, be, emb, NTOK, 16, DM);
    // 2-4. Q,K,V projections
    gemm_kernel<false><<<dim3(4, 128), blk, 0, stream>>>(emb, Wq, bq, Qb, NTOK, DM, DM);
    gemm_kernel<false><<<dim3(4, 128), blk, 0, stream>>>(emb, Wk, bk, Kb, NTOK, DM, DM);
    gemm_kernel<false><<<dim3(4, 128), blk, 0, stream>>>(emb, Wv, bv, Vb, NTOK, DM, DM);
    // 5. energy -> attn region of d_out
    energy_kernel<<<dim3(SEQ / 64, SEQ / 64, BATCH * NH), blk, 0, stream>>>(Qb, Kb, attn);
    // 6+7. fused softmax (in-place) + ctx = attn @ V
    smpv_kernel<<<dim3(SEQ / QR, BATCH * NH), blk, 0, stream>>>(attn, Vb, ctx);
    // 8. attn_out = ctx@Wo + bo
    gemm_kernel<false><<<dim3(4, 128), blk, 0, stream>>>(ctx, Wo, bo, ao, NTOK, DM, DM);
    // 9. x = LN(emb + attn_out)
    ln_kernel<<<dim3(NTOK), blk, 0, stream>>>(emb, ao, g1, b1, x);
    // 10. h = relu(x@W1 + c1)        [8192,256]x[256,512]
    gemm_kernel<true><<<dim3(8, 128), blk, 0, stream>>>(x, W1, c1, hb, NTOK, DM, DFF);
    // 11. ff = h@W2 + c2             [8192,512]x[512,256]
    gemm_kernel<false><<<dim3(4, 128), blk, 0, stream>>>(hb, W2, c2, ff, NTOK, DFF, DM);
    // 12. out = LN(x + ff)
    ln_kernel<<<dim3(NTOK), blk, 0, stream>>>(x, ff, g2, b2, out);
}

// Round 8
// 839.946 us; speedup vs baseline: 1.4346x; 1.4346x over previous
//
#include <hip/hip_runtime.h>
#include <math.h>

#define SEQ 2048
#define DM 256
#define NH 8
#define HD 32
#define DFF 512
#define BATCH 4
#define NTOK 8192
#define EPS 1e-5f
#define RS 0.17677669529663687f   // 1/sqrt(32)

typedef __attribute__((ext_vector_type(8))) short bf16x8;   // 8 bf16 in 4 VGPRs
typedef __attribute__((ext_vector_type(4))) float f32x4;

#define MFMA16(a, b, c) __builtin_amdgcn_mfma_f32_16x16x32_bf16(a, b, c, 0, 0, 0)

__device__ __forceinline__ unsigned short f2bf(float f) {
    unsigned int u = __float_as_uint(f);
    u = (u + 0x7FFFu + ((u >> 16) & 1u)) >> 16;   // RNE
    return (unsigned short)u;
}
__device__ __forceinline__ float bf2f(unsigned short h) {
    return __uint_as_float(((unsigned int)h) << 16);
}

// ------------------------------------------------ fp32 [K][N] -> bf16 [N][K]
__global__ __launch_bounds__(256) void transpose_bf(
    const float* __restrict__ src, unsigned short* __restrict__ dst, int K, int N)
{
    __shared__ float t[16][17];
    const int tx = threadIdx.x & 15, ty = threadIdx.x >> 4;
    const int n0 = blockIdx.x * 16, k0 = blockIdx.y * 16;
    t[ty][tx] = src[(size_t)(k0 + ty) * N + n0 + tx];
    __syncthreads();
    dst[(size_t)(n0 + ty) * K + k0 + tx] = f2bf(t[tx][ty]);
}

// ------------------------------------------------ emb = src@We + be (K=16)
__global__ __launch_bounds__(256) void embed_kernel(
    const float* __restrict__ src, const float* __restrict__ We,
    const float* __restrict__ be, float* __restrict__ emb32,
    unsigned short* __restrict__ embb)
{
    __shared__ float s16[16];
    const int row = blockIdx.x, tid = threadIdx.x;
    if (tid < 16) s16[tid] = src[(size_t)row * 16 + tid];
    __syncthreads();
    float acc = be[tid];
    #pragma unroll
    for (int k = 0; k < 16; k++) acc = fmaf(s16[k], We[k * DM + tid], acc);
    emb32[(size_t)row * DM + tid] = acc;
    embb[(size_t)row * DM + tid] = f2bf(acc);
}

// ------------------------------------------------ bf16 MFMA GEMM, direct-global
// C[M,N] = act(A_bf[M,K] @ W, W given as Wt_bf[N,K]) + bias
// OM: 0 = fp32 out, 1 = bf16 token out, 2 = bf16 V-transposed out (Vt[b][h][d][s])
template<int OM, bool RELU>
__global__ __launch_bounds__(256) void gemm_bf(
    const unsigned short* __restrict__ A, const unsigned short* __restrict__ Wt,
    const float* __restrict__ bias, void* __restrict__ C, int M, int N, int K)
{
    const int tid = threadIdx.x;
    const int w = tid >> 6, lane = tid & 63;
    const int lo = lane & 15, hi = lane >> 4;
    const int m0 = blockIdx.y * 64 + (w >> 1) * 32;
    const int n0 = blockIdx.x * 64 + (w & 1) * 32;
    f32x4 acc[2][2] = {};
    const unsigned short* Ap0 = A + (size_t)(m0 + lo) * K + hi * 8;
    const unsigned short* Ap1 = Ap0 + (size_t)16 * K;
    const unsigned short* Bp0 = Wt + (size_t)(n0 + lo) * K + hi * 8;
    const unsigned short* Bp1 = Bp0 + (size_t)16 * K;
    for (int k0 = 0; k0 < K; k0 += 32) {
        bf16x8 a0 = *(const bf16x8*)(Ap0 + k0);
        bf16x8 a1 = *(const bf16x8*)(Ap1 + k0);
        bf16x8 b0 = *(const bf16x8*)(Bp0 + k0);
        bf16x8 b1 = *(const bf16x8*)(Bp1 + k0);
        acc[0][0] = MFMA16(a0, b0, acc[0][0]);
        acc[0][1] = MFMA16(a0, b1, acc[0][1]);
        acc[1][0] = MFMA16(a1, b0, acc[1][0]);
        acc[1][1] = MFMA16(a1, b1, acc[1][1]);
    }
    #pragma unroll
    for (int i = 0; i < 2; i++)
        #pragma unroll
        for (int j = 0; j < 2; j++) {
            const int n = n0 + j * 16 + lo;
            const float bz = bias[n];
            #pragma unroll
            for (int r = 0; r < 4; r++) {
                const int m = m0 + i * 16 + 4 * hi + r;
                float v = acc[i][j][r] + bz;
                if (RELU) v = fmaxf(v, 0.f);
                if (OM == 0) {
                    ((float*)C)[(size_t)m * N + n] = v;
                } else if (OM == 1) {
                    ((unsigned short*)C)[(size_t)m * N + n] = f2bf(v);
                } else {
                    const int b = m >> 11, s = m & 2047;
                    const int hh = n >> 5, d = n & 31;
                    ((unsigned short*)C)[((size_t)(b * NH + hh) * HD + d) * SEQ + s] = f2bf(v);
                }
            }
        }
}

// ------------------------------------------------ fused flash attention
// Block: 4 waves x 16 q-rows = 64 q-rows of one (b,h).
// Pass A: online (m,l) per q-row over QK^T tiles (recomputed, never stored).
// Pass B: recompute S, P=exp(S-m)/l -> fp32 attn out; P->bf16 via LDS
//         transpose bounce -> PV MFMA against pre-transposed Vt.
__global__ __launch_bounds__(256) void fused_attn(
    const unsigned short* __restrict__ Qb, const unsigned short* __restrict__ Kb,
    const unsigned short* __restrict__ Vt, float* __restrict__ attn,
    unsigned short* __restrict__ ctxb)
{
    __shared__ unsigned short Pt[4][16][40];   // [wave][q][key 0..31, pad 40]
    const int tid = threadIdx.x;
    const int w = tid >> 6, lane = tid & 63;
    const int lo = lane & 15, hi = lane >> 4;
    const int bh = blockIdx.y, b = bh >> 3, h = bh & 7;
    const int q0 = blockIdx.x * 64 + w * 16;

    const bf16x8 qf = *(const bf16x8*)(Qb + ((size_t)(b * SEQ) + q0 + lo) * DM + h * HD + hi * 8);
    const unsigned short* Kbase = Kb + (size_t)(b * SEQ) * DM + h * HD + hi * 8;
    const f32x4 zero = {0.f, 0.f, 0.f, 0.f};

    // ---- pass A: stats
    float m[4] = {-3.0e38f, -3.0e38f, -3.0e38f, -3.0e38f};
    float l[4] = {};
    for (int kt = 0; kt < SEQ; kt += 16) {
        bf16x8 kf = *(const bf16x8*)(Kbase + (size_t)(kt + lo) * DM);
        f32x4 s = MFMA16(qf, kf, zero);
        #pragma unroll
        for (int r = 0; r < 4; r++) {
            float v = s[r] * RS;
            float nm = fmaxf(m[r], v);
            l[r] = l[r] * __expf(m[r] - nm) + __expf(v - nm);
            m[r] = nm;
        }
    }
    #pragma unroll
    for (int off = 1; off < 16; off <<= 1) {
        #pragma unroll
        for (int r = 0; r < 4; r++) {
            float m2 = __shfl_xor(m[r], off);
            float l2 = __shfl_xor(l[r], off);
            float M = fmaxf(m[r], m2);
            l[r] = l[r] * __expf(m[r] - M) + l2 * __expf(m2 - M);
            m[r] = M;
        }
    }
    float inv[4];
    #pragma unroll
    for (int r = 0; r < 4; r++) inv[r] = 1.f / l[r];

    // ---- pass B: P out + PV
    f32x4 acc0 = {}, acc1 = {};
    float* attnBase = attn + ((size_t)bh * SEQ + q0) * SEQ;
    const unsigned short* Vtb = Vt + (size_t)bh * HD * SEQ;
    for (int kt = 0; kt < SEQ; kt += 32) {
        #pragma unroll
        for (int sub = 0; sub < 2; sub++) {
            const int k16 = kt + sub * 16;
            bf16x8 kf = *(const bf16x8*)(Kbase + (size_t)(k16 + lo) * DM);
            f32x4 s = MFMA16(qf, kf, zero);
            #pragma unroll
            for (int r = 0; r < 4; r++) {
                float p = __expf(s[r] * RS - m[r]) * inv[r];
                attnBase[(size_t)(4 * hi + r) * SEQ + k16 + lo] = p;
                Pt[w][4 * hi + r][sub * 16 + lo] = f2bf(p);
            }
        }
        __builtin_amdgcn_s_waitcnt(0);   // ds_write visible to own wave before read
        bf16x8 pa = *(const bf16x8*)&Pt[w][lo][hi * 8];
        bf16x8 v0 = *(const bf16x8*)(Vtb + (size_t)lo * SEQ + kt + hi * 8);
        bf16x8 v1 = *(const bf16x8*)(Vtb + (size_t)(16 + lo) * SEQ + kt + hi * 8);
        acc0 = MFMA16(pa, v0, acc0);
        acc1 = MFMA16(pa, v1, acc1);
    }
    unsigned short* ctxp = ctxb + ((size_t)(b * SEQ) + q0) * DM + h * HD;
    #pragma unroll
    for (int r = 0; r < 4; r++) {
        ctxp[(size_t)(4 * hi + r) * DM + lo]      = f2bf(acc0[r]);
        ctxp[(size_t)(4 * hi + r) * DM + 16 + lo] = f2bf(acc1[r]);
    }
}

// ------------------------------------------------ residual + LayerNorm
template<bool RBF16>
__global__ __launch_bounds__(256) void ln_kernel(
    const float* __restrict__ A, const void* __restrict__ R,
    const float* __restrict__ g, const float* __restrict__ bb,
    float* __restrict__ O32, unsigned short* __restrict__ Ob)
{
    __shared__ float sm[4];
    const size_t row = blockIdx.x;
    const int tid = threadIdx.x;
    float r = RBF16 ? bf2f(((const unsigned short*)R)[row * DM + tid])
                    : ((const float*)R)[row * DM + tid];
    float v = A[row * DM + tid] + r;
    float s = v;
    #pragma unroll
    for (int o = 32; o > 0; o >>= 1) s += __shfl_xor(s, o);
    if ((tid & 63) == 0) sm[tid >> 6] = s;
    __syncthreads();
    s = sm[0] + sm[1] + sm[2] + sm[3];
    __syncthreads();
    float mu = s * (1.f / DM);
    float d = v - mu;
    float s2 = d * d;
    #pragma unroll
    for (int o = 32; o > 0; o >>= 1) s2 += __shfl_xor(s2, o);
    if ((tid & 63) == 0) sm[tid >> 6] = s2;
    __syncthreads();
    s2 = sm[0] + sm[1] + sm[2] + sm[3];
    float rstd = rsqrtf(s2 * (1.f / DM) + EPS);
    float o = d * rstd * g[tid] + bb[tid];
    O32[row * DM + tid] = o;
    if (Ob) Ob[row * DM + tid] = f2bf(o);
}

// ------------------------------------------------ launch
extern "C" void kernel_launch(void* const* d_in, const int* in_sizes, int n_in,
                              void* d_out, int out_size, void* d_ws, size_t ws_size,
                              hipStream_t stream)
{
    const float* src = (const float*)d_in[0];
    const float* We  = (const float*)d_in[1];
    const float* be  = (const float*)d_in[2];
    const float* Wq  = (const float*)d_in[3];
    const float* bq  = (const float*)d_in[4];
    const float* Wk  = (const float*)d_in[5];
    const float* bk  = (const float*)d_in[6];
    const float* Wv  = (const float*)d_in[7];
    const float* bv  = (const float*)d_in[8];
    const float* Wo  = (const float*)d_in[9];
    const float* bo  = (const float*)d_in[10];
    const float* g1  = (const float*)d_in[11];
    const float* b1  = (const float*)d_in[12];
    const float* g2  = (const float*)d_in[13];
    const float* b2  = (const float*)d_in[14];
    const float* W1  = (const float*)d_in[15];
    const float* c1  = (const float*)d_in[16];
    const float* W2  = (const float*)d_in[17];
    const float* c2  = (const float*)d_in[18];

    float* out  = (float*)d_out;                     // [8192,256] fp32
    float* attn = out + (size_t)NTOK * DM;           // [32,2048,2048] fp32

    char* ws = (char*)d_ws;
    const size_t MB = 1024 * 1024;
    float*          emb32 = (float*)(ws);                    // [0,8)MB ; later x32 (in-place LN)
    unsigned short* embb  = (unsigned short*)(ws + 8 * MB);  // [8,12) ; later ctxb, then ffb
    unsigned short* Qbf   = (unsigned short*)(ws + 12 * MB); // [12,16); later ao(lo)/hb(lo)
    unsigned short* Kbf   = (unsigned short*)(ws + 16 * MB); // [16,20)
    unsigned short* Vtb   = (unsigned short*)(ws + 20 * MB); // [20,24); later xb
    unsigned short* Wqt   = (unsigned short*)(ws + 24 * MB);
    unsigned short* Wkt   = (unsigned short*)(ws + 24 * MB + 128 * 1024);
    unsigned short* Wvt   = (unsigned short*)(ws + 24 * MB + 256 * 1024);
    unsigned short* Wot   = (unsigned short*)(ws + 24 * MB + 384 * 1024);
    unsigned short* W1t   = (unsigned short*)(ws + 24 * MB + 512 * 1024);
    unsigned short* W2t   = (unsigned short*)(ws + 24 * MB + 768 * 1024);
    // reuse map (all dead/live sets checked):
    unsigned short* ctxb = embb;                       // ctx bf16 (embb dead after V proj)
    float*          ao   = (float*)(ws + 12 * MB);     // attn_out fp32 8MB (Qbf+Kbf dead)
    float*          x32  = emb32;                      // LN1 in-place
    unsigned short* xb   = Vtb;                        // x bf16 (Vt dead after attn)
    unsigned short* hb   = (unsigned short*)(ws + 12 * MB); // ffn hidden bf16 8MB (ao dead after LN1)
    unsigned short* ffb  = embb;                       // ff bf16 (ctxb dead after Wo)

    dim3 blk(256);
    // 0. weights -> transposed bf16
    transpose_bf<<<dim3(16, 16), blk, 0, stream>>>(Wq, Wqt, DM, DM);
    transpose_bf<<<dim3(16, 16), blk, 0, stream>>>(Wk, Wkt, DM, DM);
    transpose_bf<<<dim3(16, 16), blk, 0, stream>>>(Wv, Wvt, DM, DM);
    transpose_bf<<<dim3(16, 16), blk, 0, stream>>>(Wo, Wot, DM, DM);
    transpose_bf<<<dim3(32, 16), blk, 0, stream>>>(W1, W1t, DM, DFF);
    transpose_bf<<<dim3(16, 32), blk, 0, stream>>>(W2, W2t, DFF, DM);
    // 1. embed
    embed_kernel<<<dim3(NTOK), blk, 0, stream>>>(src, We, be, emb32, embb);
    // 2-4. Q,K (token layout bf16), V (transposed bf16)
    gemm_bf<1, false><<<dim3(4, 128), blk, 0, stream>>>(embb, Wqt, bq, Qbf, NTOK, DM, DM);
    gemm_bf<1, false><<<dim3(4, 128), blk, 0, stream>>>(embb, Wkt, bk, Kbf, NTOK, DM, DM);
    gemm_bf<2, false><<<dim3(4, 128), blk, 0, stream>>>(embb, Wvt, bv, Vtb, NTOK, DM, DM);
    // 5. fused attention: attn (fp32, d_out) + ctx (bf16)
    fused_attn<<<dim3(SEQ / 64, BATCH * NH), blk, 0, stream>>>(Qbf, Kbf, Vtb, attn, ctxb);
    // 6. attn_out = ctx@Wo + bo (fp32)
    gemm_bf<0, false><<<dim3(4, 128), blk, 0, stream>>>(ctxb, Wot, bo, ao, NTOK, DM, DM);
    // 7. x = LN(emb + attn_out) -> fp32 + bf16
    ln_kernel<false><<<dim3(NTOK), blk, 0, stream>>>(emb32, ao, g1, b1, x32, xb);
    // 8. h = relu(x@W1 + c1) (bf16)
    gemm_bf<1, true><<<dim3(8, 128), blk, 0, stream>>>(xb, W1t, c1, hb, NTOK, DFF, DM);
    // 9. ff = h@W2 + c2 (bf16)
    gemm_bf<1, false><<<dim3(4, 128), blk, 0, stream>>>(hb, W2t, c2, ffb, NTOK, DM, DFF);
    // 10. out = LN(x + ff)
    ln_kernel<true><<<dim3(NTOK), blk, 0, stream>>>(x32, ffb, g2, b2, out, nullptr);
}

// Round 9
// 828.753 us; speedup vs baseline: 1.4539x; 1.0135x over previous
//
#include <hip/hip_runtime.h>
#include <math.h>

#define SEQ 2048
#define DM 256
#define NH 8
#define HD 32
#define DFF 512
#define BATCH 4
#define NTOK 8192
#define EPS 1e-5f
#define RS 0.17677669529663687f   // 1/sqrt(32)

typedef __attribute__((ext_vector_type(8))) short bf16x8;   // 8 bf16 in 4 VGPRs
typedef __attribute__((ext_vector_type(4))) float f32x4;
typedef __attribute__((ext_vector_type(4))) unsigned short u16x4;

#define MFMA16(a, b, c) __builtin_amdgcn_mfma_f32_16x16x32_bf16(a, b, c, 0, 0, 0)

__device__ __forceinline__ unsigned short f2bf(float f) {
    unsigned int u = __float_as_uint(f);
    u = (u + 0x7FFFu + ((u >> 16) & 1u)) >> 16;   // RNE
    return (unsigned short)u;
}
__device__ __forceinline__ float bf2f(unsigned short h) {
    return __uint_as_float(((unsigned int)h) << 16);
}

// ------------------------------------------------ fp32 [K][N] -> bf16 [N][K]
__global__ __launch_bounds__(256) void transpose_bf(
    const float* __restrict__ src, unsigned short* __restrict__ dst, int K, int N)
{
    __shared__ float t[16][17];
    const int tx = threadIdx.x & 15, ty = threadIdx.x >> 4;
    const int n0 = blockIdx.x * 16, k0 = blockIdx.y * 16;
    t[ty][tx] = src[(size_t)(k0 + ty) * N + n0 + tx];
    __syncthreads();
    dst[(size_t)(n0 + ty) * K + k0 + tx] = f2bf(t[tx][ty]);
}

// ------------------------------------------------ emb = src@We + be (K=16)
__global__ __launch_bounds__(256) void embed_kernel(
    const float* __restrict__ src, const float* __restrict__ We,
    const float* __restrict__ be, float* __restrict__ emb32,
    unsigned short* __restrict__ embb)
{
    __shared__ float s16[16];
    const int row = blockIdx.x, tid = threadIdx.x;
    if (tid < 16) s16[tid] = src[(size_t)row * 16 + tid];
    __syncthreads();
    float acc = be[tid];
    #pragma unroll
    for (int k = 0; k < 16; k++) acc = fmaf(s16[k], We[k * DM + tid], acc);
    emb32[(size_t)row * DM + tid] = acc;
    embb[(size_t)row * DM + tid] = f2bf(acc);
}

// ------------------------------------------------ fused QKV projection
// One dispatch: C = embb @ {Wq|Wk|Wv} + {bq|bk|bv}.
// WQKVt = [768][256] bf16 (transposed weights, contiguous). blockIdx.x: 0-3 Q,
// 4-7 K, 8-11 V (64 cols each). Q,K -> token layout bf16; V -> Vt[b][h][d][s].
__global__ __launch_bounds__(256) void qkv_gemm(
    const unsigned short* __restrict__ A, const unsigned short* __restrict__ WQKVt,
    const float* __restrict__ bq, const float* __restrict__ bk,
    const float* __restrict__ bv,
    unsigned short* __restrict__ Qb, unsigned short* __restrict__ Kb,
    unsigned short* __restrict__ Vt)
{
    const int tid = threadIdx.x;
    const int w = tid >> 6, lane = tid & 63;
    const int lo = lane & 15, hi = lane >> 4;
    const int which = blockIdx.x >> 2;                  // 0 Q, 1 K, 2 V
    const float* bias = which == 0 ? bq : (which == 1 ? bk : bv);
    const int m0 = blockIdx.y * 64 + (w >> 1) * 32;
    const int n0g = blockIdx.x * 64 + (w & 1) * 32;     // col in [0,768)
    f32x4 acc[2][2] = {};
    const unsigned short* Ap0 = A + (size_t)(m0 + lo) * DM + hi * 8;
    const unsigned short* Ap1 = Ap0 + (size_t)16 * DM;
    const unsigned short* Bp0 = WQKVt + (size_t)(n0g + lo) * DM + hi * 8;
    const unsigned short* Bp1 = Bp0 + (size_t)16 * DM;
    #pragma unroll
    for (int k0 = 0; k0 < DM; k0 += 32) {
        bf16x8 a0 = *(const bf16x8*)(Ap0 + k0);
        bf16x8 a1 = *(const bf16x8*)(Ap1 + k0);
        bf16x8 b0 = *(const bf16x8*)(Bp0 + k0);
        bf16x8 b1 = *(const bf16x8*)(Bp1 + k0);
        acc[0][0] = MFMA16(a0, b0, acc[0][0]);
        acc[0][1] = MFMA16(a0, b1, acc[0][1]);
        acc[1][0] = MFMA16(a1, b0, acc[1][0]);
        acc[1][1] = MFMA16(a1, b1, acc[1][1]);
    }
    unsigned short* tok = which == 0 ? Qb : Kb;
    #pragma unroll
    for (int i = 0; i < 2; i++)
        #pragma unroll
        for (int j = 0; j < 2; j++) {
            const int nl = (n0g & 255) + j * 16 + lo;    // col within weight set
            const float bz = bias[nl];
            #pragma unroll
            for (int r = 0; r < 4; r++) {
                const int m = m0 + i * 16 + 4 * hi + r;
                float v = acc[i][j][r] + bz;
                if (which < 2) {
                    tok[(size_t)m * DM + nl] = f2bf(v);
                } else {
                    const int b = m >> 11, s = m & 2047;
                    const int hh = nl >> 5, d = nl & 31;
                    Vt[((size_t)(b * NH + hh) * HD + d) * SEQ + s] = f2bf(v);
                }
            }
        }
}

// ------------------------------------------------ generic bf16 MFMA GEMM
// OM: 0 = fp32 out, 1 = bf16 token out
template<int OM, bool RELU>
__global__ __launch_bounds__(256) void gemm_bf(
    const unsigned short* __restrict__ A, const unsigned short* __restrict__ Wt,
    const float* __restrict__ bias, void* __restrict__ C, int M, int N, int K)
{
    const int tid = threadIdx.x;
    const int w = tid >> 6, lane = tid & 63;
    const int lo = lane & 15, hi = lane >> 4;
    const int m0 = blockIdx.y * 64 + (w >> 1) * 32;
    const int n0 = blockIdx.x * 64 + (w & 1) * 32;
    f32x4 acc[2][2] = {};
    const unsigned short* Ap0 = A + (size_t)(m0 + lo) * K + hi * 8;
    const unsigned short* Ap1 = Ap0 + (size_t)16 * K;
    const unsigned short* Bp0 = Wt + (size_t)(n0 + lo) * K + hi * 8;
    const unsigned short* Bp1 = Bp0 + (size_t)16 * K;
    for (int k0 = 0; k0 < K; k0 += 32) {
        bf16x8 a0 = *(const bf16x8*)(Ap0 + k0);
        bf16x8 a1 = *(const bf16x8*)(Ap1 + k0);
        bf16x8 b0 = *(const bf16x8*)(Bp0 + k0);
        bf16x8 b1 = *(const bf16x8*)(Bp1 + k0);
        acc[0][0] = MFMA16(a0, b0, acc[0][0]);
        acc[0][1] = MFMA16(a0, b1, acc[0][1]);
        acc[1][0] = MFMA16(a1, b0, acc[1][0]);
        acc[1][1] = MFMA16(a1, b1, acc[1][1]);
    }
    #pragma unroll
    for (int i = 0; i < 2; i++)
        #pragma unroll
        for (int j = 0; j < 2; j++) {
            const int n = n0 + j * 16 + lo;
            const float bz = bias[n];
            #pragma unroll
            for (int r = 0; r < 4; r++) {
                const int m = m0 + i * 16 + 4 * hi + r;
                float v = acc[i][j][r] + bz;
                if (RELU) v = fmaxf(v, 0.f);
                if (OM == 0) ((float*)C)[(size_t)m * N + n] = v;
                else         ((unsigned short*)C)[(size_t)m * N + n] = f2bf(v);
            }
        }
}

// ------------------------------------------------ fused flash attention
// Block: 4 waves x 16 q-rows. Pass A: online (m,l) (1 exp per score).
// Pass B (64-key tiles): recompute S, P -> bf16 LDS; PV MFMA from LDS;
// attn written fp32 via float4 from LDS readback (256B-contiguous rows).
__global__ __launch_bounds__(256) void fused_attn(
    const unsigned short* __restrict__ Qb, const unsigned short* __restrict__ Kb,
    const unsigned short* __restrict__ Vt, float* __restrict__ attn,
    unsigned short* __restrict__ ctxb)
{
    __shared__ unsigned short Pt[4][16][72];   // [wave][q][key 0..63, pad 72]
    const int tid = threadIdx.x;
    const int w = tid >> 6, lane = tid & 63;
    const int lo = lane & 15, hi = lane >> 4;
    const int bh = blockIdx.y, b = bh >> 3, h = bh & 7;
    const int q0 = blockIdx.x * 64 + w * 16;

    const bf16x8 qf = *(const bf16x8*)(Qb + ((size_t)(b * SEQ) + q0 + lo) * DM + h * HD + hi * 8);
    const unsigned short* Kbase = Kb + (size_t)(b * SEQ) * DM + h * HD + hi * 8;
    const f32x4 zero = {0.f, 0.f, 0.f, 0.f};

    // ---- pass A: stats (1 exp/score branchless online update)
    float m[4] = {-3.0e38f, -3.0e38f, -3.0e38f, -3.0e38f};
    float l[4] = {};
    for (int kt = 0; kt < SEQ; kt += 16) {
        bf16x8 kf = *(const bf16x8*)(Kbase + (size_t)(kt + lo) * DM);
        f32x4 s = MFMA16(qf, kf, zero);
        #pragma unroll
        for (int r = 0; r < 4; r++) {
            float v = s[r] * RS;
            float d = v - m[r];
            float e = __expf(-fabsf(d));
            l[r] = d > 0.f ? fmaf(l[r], e, 1.f) : (l[r] + e);
            m[r] = fmaxf(m[r], v);
        }
    }
    #pragma unroll
    for (int off = 1; off < 16; off <<= 1) {
        #pragma unroll
        for (int r = 0; r < 4; r++) {
            float m2 = __shfl_xor(m[r], off);
            float l2 = __shfl_xor(l[r], off);
            float M = fmaxf(m[r], m2);
            l[r] = l[r] * __expf(m[r] - M) + l2 * __expf(m2 - M);
            m[r] = M;
        }
    }
    float inv[4];
    #pragma unroll
    for (int r = 0; r < 4; r++) inv[r] = 1.f / l[r];

    // ---- pass B: 64-key tiles
    f32x4 acc0 = {}, acc1 = {};
    float* attnBase = attn + ((size_t)bh * SEQ + q0) * SEQ;
    const unsigned short* Vtb = Vt + (size_t)bh * HD * SEQ;
    for (int kt = 0; kt < SEQ; kt += 64) {
        #pragma unroll
        for (int sub = 0; sub < 4; sub++) {
            const int k16 = kt + sub * 16;
            bf16x8 kf = *(const bf16x8*)(Kbase + (size_t)(k16 + lo) * DM);
            f32x4 s = MFMA16(qf, kf, zero);
            #pragma unroll
            for (int r = 0; r < 4; r++) {
                float p = __expf(s[r] * RS - m[r]) * inv[r];
                Pt[w][4 * hi + r][sub * 16 + lo] = f2bf(p);
            }
        }
        asm volatile("s_waitcnt lgkmcnt(0)" ::: "memory");
        __builtin_amdgcn_sched_barrier(0);
        // PV: two 32-key chunks
        bf16x8 pa0 = *(const bf16x8*)&Pt[w][lo][hi * 8];
        bf16x8 pa1 = *(const bf16x8*)&Pt[w][lo][32 + hi * 8];
        bf16x8 v00 = *(const bf16x8*)(Vtb + (size_t)lo * SEQ + kt + hi * 8);
        bf16x8 v01 = *(const bf16x8*)(Vtb + (size_t)(16 + lo) * SEQ + kt + hi * 8);
        bf16x8 v10 = *(const bf16x8*)(Vtb + (size_t)lo * SEQ + kt + 32 + hi * 8);
        bf16x8 v11 = *(const bf16x8*)(Vtb + (size_t)(16 + lo) * SEQ + kt + 32 + hi * 8);
        acc0 = MFMA16(pa0, v00, acc0);
        acc1 = MFMA16(pa0, v01, acc1);
        acc0 = MFMA16(pa1, v10, acc0);
        acc1 = MFMA16(pa1, v11, acc1);
        // attn store: float4, 256B-contiguous per row
        #pragma unroll
        for (int s4 = 0; s4 < 4; s4++) {
            const int row = s4 * 4 + hi;
            const int col = lo * 4;
            u16x4 u = *(const u16x4*)&Pt[w][row][col];
            float4 f;
            f.x = bf2f(u.x); f.y = bf2f(u.y); f.z = bf2f(u.z); f.w = bf2f(u.w);
            *reinterpret_cast<float4*>(&attnBase[(size_t)row * SEQ + kt + col]) = f;
        }
    }
    unsigned short* ctxp = ctxb + ((size_t)(b * SEQ) + q0) * DM + h * HD;
    #pragma unroll
    for (int r = 0; r < 4; r++) {
        ctxp[(size_t)(4 * hi + r) * DM + lo]      = f2bf(acc0[r]);
        ctxp[(size_t)(4 * hi + r) * DM + 16 + lo] = f2bf(acc1[r]);
    }
}

// ------------------------------------------------ residual + LayerNorm
template<bool RBF16>
__global__ __launch_bounds__(256) void ln_kernel(
    const float* __restrict__ A, const void* __restrict__ R,
    const float* __restrict__ g, const float* __restrict__ bb,
    float* __restrict__ O32, unsigned short* __restrict__ Ob)
{
    __shared__ float sm[4];
    const size_t row = blockIdx.x;
    const int tid = threadIdx.x;
    float r = RBF16 ? bf2f(((const unsigned short*)R)[row * DM + tid])
                    : ((const float*)R)[row * DM + tid];
    float v = A[row * DM + tid] + r;
    float s = v;
    #pragma unroll
    for (int o = 32; o > 0; o >>= 1) s += __shfl_xor(s, o);
    if ((tid & 63) == 0) sm[tid >> 6] = s;
    __syncthreads();
    s = sm[0] + sm[1] + sm[2] + sm[3];
    __syncthreads();
    float mu = s * (1.f / DM);
    float d = v - mu;
    float s2 = d * d;
    #pragma unroll
    for (int o = 32; o > 0; o >>= 1) s2 += __shfl_xor(s2, o);
    if ((tid & 63) == 0) sm[tid >> 6] = s2;
    __syncthreads();
    s2 = sm[0] + sm[1] + sm[2] + sm[3];
    float rstd = rsqrtf(s2 * (1.f / DM) + EPS);
    float o = d * rstd * g[tid] + bb[tid];
    O32[row * DM + tid] = o;
    if (Ob) Ob[row * DM + tid] = f2bf(o);
}

// ------------------------------------------------ launch
extern "C" void kernel_launch(void* const* d_in, const int* in_sizes, int n_in,
                              void* d_out, int out_size, void* d_ws, size_t ws_size,
                              hipStream_t stream)
{
    const float* src = (const float*)d_in[0];
    const float* We  = (const float*)d_in[1];
    const float* be  = (const float*)d_in[2];
    const float* Wq  = (const float*)d_in[3];
    const float* bq  = (const float*)d_in[4];
    const float* Wk  = (const float*)d_in[5];
    const float* bk  = (const float*)d_in[6];
    const float* Wv  = (const float*)d_in[7];
    const float* bv  = (const float*)d_in[8];
    const float* Wo  = (const float*)d_in[9];
    const float* bo  = (const float*)d_in[10];
    const float* g1  = (const float*)d_in[11];
    const float* b1  = (const float*)d_in[12];
    const float* g2  = (const float*)d_in[13];
    const float* b2  = (const float*)d_in[14];
    const float* W1  = (const float*)d_in[15];
    const float* c1  = (const float*)d_in[16];
    const float* W2  = (const float*)d_in[17];
    const float* c2  = (const float*)d_in[18];

    float* out  = (float*)d_out;                     // [8192,256] fp32
    float* attn = out + (size_t)NTOK * DM;           // [32,2048,2048] fp32

    char* ws = (char*)d_ws;
    const size_t MB = 1024 * 1024;
    float*          emb32 = (float*)(ws);                    // [0,8)MB ; later x32
    unsigned short* embb  = (unsigned short*)(ws + 8 * MB);  // [8,12); later ctxb/ffb
    unsigned short* Qbf   = (unsigned short*)(ws + 12 * MB); // [12,16)
    unsigned short* Kbf   = (unsigned short*)(ws + 16 * MB); // [16,20)
    unsigned short* Vtb   = (unsigned short*)(ws + 20 * MB); // [20,24); later xb
    unsigned short* WQKVt = (unsigned short*)(ws + 24 * MB); // [768][256] contiguous
    unsigned short* Wqt   = WQKVt;
    unsigned short* Wkt   = (unsigned short*)(ws + 24 * MB + 128 * 1024);
    unsigned short* Wvt   = (unsigned short*)(ws + 24 * MB + 256 * 1024);
    unsigned short* Wot   = (unsigned short*)(ws + 24 * MB + 384 * 1024);
    unsigned short* W1t   = (unsigned short*)(ws + 24 * MB + 512 * 1024);
    unsigned short* W2t   = (unsigned short*)(ws + 24 * MB + 768 * 1024);
    // reuse map:
    unsigned short* ctxb = embb;                       // embb dead after QKV
    float*          ao   = (float*)(ws + 12 * MB);     // Qbf+Kbf dead after attn
    float*          x32  = emb32;                      // LN1 in-place
    unsigned short* xb   = Vtb;                        // Vt dead after attn
    unsigned short* hb   = (unsigned short*)(ws + 12 * MB); // ao dead after LN1
    unsigned short* ffb  = embb;                       // ctxb dead after Wo

    dim3 blk(256);
    // 0. weights -> transposed bf16 (Wq/Wk/Wv land contiguous in WQKVt)
    transpose_bf<<<dim3(16, 16), blk, 0, stream>>>(Wq, Wqt, DM, DM);
    transpose_bf<<<dim3(16, 16), blk, 0, stream>>>(Wk, Wkt, DM, DM);
    transpose_bf<<<dim3(16, 16), blk, 0, stream>>>(Wv, Wvt, DM, DM);
    transpose_bf<<<dim3(16, 16), blk, 0, stream>>>(Wo, Wot, DM, DM);
    transpose_bf<<<dim3(32, 16), blk, 0, stream>>>(W1, W1t, DM, DFF);
    transpose_bf<<<dim3(16, 32), blk, 0, stream>>>(W2, W2t, DFF, DM);
    // 1. embed
    embed_kernel<<<dim3(NTOK), blk, 0, stream>>>(src, We, be, emb32, embb);
    // 2. fused QKV projection
    qkv_gemm<<<dim3(12, 128), blk, 0, stream>>>(embb, WQKVt, bq, bk, bv, Qbf, Kbf, Vtb);
    // 3. fused attention: attn (fp32, d_out) + ctx (bf16)
    fused_attn<<<dim3(SEQ / 64, BATCH * NH), blk, 0, stream>>>(Qbf, Kbf, Vtb, attn, ctxb);
    // 4. attn_out = ctx@Wo + bo (fp32)
    gemm_bf<0, false><<<dim3(4, 128), blk, 0, stream>>>(ctxb, Wot, bo, ao, NTOK, DM, DM);
    // 5. x = LN(emb + attn_out) -> fp32 + bf16
    ln_kernel<false><<<dim3(NTOK), blk, 0, stream>>>(emb32, ao, g1, b1, x32, xb);
    // 6. h = relu(x@W1 + c1) (bf16)
    gemm_bf<1, true><<<dim3(8, 128), blk, 0, stream>>>(xb, W1t, c1, hb, NTOK, DFF, DM);
    // 7. ff = h@W2 + c2 (bf16)
    gemm_bf<1, false><<<dim3(4, 128), blk, 0, stream>>>(hb, W2t, c2, ffb, NTOK, DM, DFF);
    // 8. out = LN(x + ff)
    ln_kernel<true><<<dim3(NTOK), blk, 0, stream>>>(x32, ffb, g2, b2, out, nullptr);
}